// Round 6
// baseline (395.923 us; speedup 1.0000x reference)
//
#include <hip/hip_runtime.h>

typedef __fp16 mf16x8 __attribute__((ext_vector_type(8)));
typedef float f32x4 __attribute__((ext_vector_type(4)));

#define Tt 187
#define IST 189   // ibuf row stride (f32)
#define L2E 1.44269504088896340736f

// ---- trans-pipe activations (hw exp2 + rcp) ----
__device__ __forceinline__ float sigm(float x) {
  return __builtin_amdgcn_rcpf(1.0f + __builtin_amdgcn_exp2f(x * -L2E));
}
__device__ __forceinline__ float tanh_(float x) {
  return 1.0f - 2.0f * __builtin_amdgcn_rcpf(1.0f + __builtin_amdgcn_exp2f(x * 2.0f * L2E));
}
// ---- main-pipe activations (Padé(7,6) tanh, division-free) ----
// err <= ~4e-4 for |x|<=6 (clamped); Newton-rcp rel err ~1e-4 after 2 iters.
__device__ __forceinline__ float tanh_pade(float x) {
  float t = fminf(fmaxf(x, -6.0f), 6.0f);
  float t2 = t * t;
  float num = t * fmaf(t2, fmaf(t2, (t2 + 378.0f), 17325.0f), 135135.0f);
  float den = fmaf(t2, fmaf(t2, fmaf(t2, 28.0f, 3150.0f), 62370.0f), 135135.0f);
  float r = __builtin_bit_cast(float, 0x7EF311C3u - __builtin_bit_cast(unsigned int, den));
  r = r * (2.0f - den * r);
  r = r * (2.0f - den * r);
  return num * r;
}
__device__ __forceinline__ float sigm_pade(float x) {
  return fmaf(tanh_pade(x * 0.5f), 0.5f, 0.5f);
}

__device__ __forceinline__ unsigned int pkbits(float lo, float hi) {
  return __builtin_bit_cast(unsigned int, __builtin_amdgcn_cvt_pkrtz(lo, hi));
}
// B fragment from this lane's own hn[5] (+ x in slot element 5): k-slot 8g+jt <-> unit 4jt+g
__device__ __forceinline__ mf16x8 mkbf(const float* hn, float xsel) {
  union { unsigned int u[4]; mf16x8 v; } cv;
  cv.u[0] = pkbits(hn[0], hn[1]);
  cv.u[1] = pkbits(hn[2], hn[3]);
  cv.u[2] = pkbits(hn[4], xsel);
  cv.u[3] = 0u;
  return cv.v;
}

// Stage one layer's weights into per-lane MFMA fragments.
// A lane (m = lane&15, ka = lane>>4): j = 16*jt + m -> unit 4*jt+(m>>2), gate m&3.
// k-slot 8*ka+kk: kk<5 -> input unit 4*kk+ka ; slot 21 -> x (Wih) ; else zero pad.
// Bias in D-layout: lane (r, g) reg i -> gate i of unit 4*jt+g.
__device__ __forceinline__ void stage_layer(
    const float* __restrict__ Wih, const float* __restrict__ Whh,
    const float* __restrict__ bih, const float* __restrict__ bhh,
    int m, int g, mf16x8* A, f32x4* Bias)
{
#pragma unroll
  for (int jt = 0; jt < 5; ++jt) {
    const int unitA = 4 * jt + (m >> 2), gateA = m & 3;
    const int trow = gateA * 20 + unitA;          // torch row in [4H]
    union { __fp16 h[8]; mf16x8 v; } av;
#pragma unroll
    for (int kk = 0; kk < 8; ++kk) {
      const int s = 8 * g + kk;                   // k-slot (A's k-group == lane>>4 == g)
      float w = 0.f;
      if (kk < 5)       w = Whh[trow * 20 + 4 * kk + g];
      else if (s == 21) w = Wih[trow];
      av.h[kk] = (__fp16)w;
    }
    A[jt] = av.v;
    const int u = 4 * jt + g;
    f32x4 bv;
#pragma unroll
    for (int i = 0; i < 4; ++i) bv[i] = bih[i * 20 + u] + bhh[i * 20 + u];
    Bias[jt] = bv;
  }
}

// mixed-pipe LSTM gate block: i,f on trans pipe; g,o on main pipe (Padé);
// tanh(cc) on trans pipe. Balances the two VALU pipes ~50/50.
#define GATES(acc, jt) do {                                           \
    float ii = sigm((acc)[0]);                                        \
    float ff = sigm((acc)[1]);                                        \
    float gg = tanh_pade((acc)[2]);                                   \
    float oo = sigm_pade((acc)[3]);                                   \
    float cc = fmaf(ff, c_[jt], ii * gg);                             \
    c_[jt] = cc;                                                      \
    hn[jt] = oo * tanh_(cc);                                          \
  } while (0)

extern "C" __global__ __launch_bounds__(64) void lstm_fused(
    const float* __restrict__ inp,  const float* __restrict__ Wih1,
    const float* __restrict__ Whh1, const float* __restrict__ bih1,
    const float* __restrict__ bhh1, const float* __restrict__ Wih2,
    const float* __restrict__ Whh2, const float* __restrict__ bih2,
    const float* __restrict__ bhh2, const float* __restrict__ Wl,
    const float* __restrict__ bl,   float* __restrict__ out, int Btot)
{
  __shared__ __align__(16) float ibuf[16 * IST];   // read-only input tile

  const int lane = threadIdx.x;
  const int r = lane & 15;      // batch row within the wave's 16-row tile
  const int g = lane >> 4;      // k-chunk / unit-group id
  const int row0 = blockIdx.x * 16;

  // stage input tile, coalesced
  {
    const float* src = inp + (size_t)row0 * Tt;
    for (int i = lane; i < 16 * Tt; i += 64) {
      int rr = i / Tt, t = i - rr * Tt;
      ibuf[rr * IST + t] = src[i];
    }
  }

  mf16x8 A1[5]; f32x4 B1[5];
  stage_layer(Wih1, Whh1, bih1, bhh1, r, g, A1, B1);

  float c_[5], hn[5];
#pragma unroll
  for (int jt = 0; jt < 5; ++jt) { c_[jt] = 0.f; hn[jt] = 0.f; }

  __syncthreads();

  // ================= encoder (no LDS writes, no barriers) =================
  float xt = ibuf[r * IST];
  for (int t = 0; t < Tt; ++t) {
    float xnext = (t + 1 < Tt) ? ibuf[r * IST + t + 1] : 0.f;  // prefetch
    mf16x8 bf = mkbf(hn, (g == 2) ? xt : 0.f);
#pragma unroll
    for (int jt = 0; jt < 5; ++jt) {
      f32x4 acc = __builtin_amdgcn_mfma_f32_16x16x32_f16(A1[jt], bf, B1[jt], 0, 0, 0);
      GATES(acc, jt);
    }
    xt = xnext;
  }

  // ================= log_softmax(h_e) =================
  {
    float m = hn[0];
#pragma unroll
    for (int jt = 1; jt < 5; ++jt) m = fmaxf(m, hn[jt]);
    m = fmaxf(m, __shfl_xor(m, 16, 64));
    m = fmaxf(m, __shfl_xor(m, 32, 64));
    float s = 0.f;
#pragma unroll
    for (int jt = 0; jt < 5; ++jt) s += __builtin_amdgcn_exp2f((hn[jt] - m) * L2E);
    s += __shfl_xor(s, 16, 64);
    s += __shfl_xor(s, 32, 64);
    const float lse = m + 0.69314718055994530942f * __builtin_amdgcn_logf(s);
    float* out2 = out + (size_t)Btot * Tt;
#pragma unroll
    for (int jt = 0; jt < 5; ++jt)
      out2[(size_t)(row0 + r) * 20 + 4 * jt + g] = hn[jt] - lse;
  }

  // ================= decoder =================
  mf16x8 A2[5]; f32x4 B2[5];
  stage_layer(Wih2, Whh2, bih2, bhh2, r, g, A2, B2);
  float wl[5];
#pragma unroll
  for (int jt = 0; jt < 5; ++jt) wl[jt] = Wl[4 * jt + g];
  const float blv = bl[0];

  float ot = 0.f;
  for (int s = 0; s < Tt; ++s) {
    mf16x8 bf = mkbf(hn, (g == 2) ? ot : 0.f);
#pragma unroll
    for (int jt = 0; jt < 5; ++jt) {
      f32x4 acc = __builtin_amdgcn_mfma_f32_16x16x32_f16(A2[jt], bf, B2[jt], 0, 0, 0);
      GATES(acc, jt);
    }
    float p = hn[0] * wl[0];
#pragma unroll
    for (int jt = 1; jt < 5; ++jt) p = fmaf(hn[jt], wl[jt], p);
    p += __shfl_xor(p, 16, 64);
    p += __shfl_xor(p, 32, 64);
    ot = sigm_pade(p + blv);
    if (g == 0) out[(size_t)(row0 + r) * Tt + (186 - s)] = ot;  // pre-flipped direct store
  }
}

extern "C" void kernel_launch(void* const* d_in, const int* in_sizes, int n_in,
                              void* d_out, int out_size, void* d_ws, size_t ws_size,
                              hipStream_t stream) {
  const float* inp  = (const float*)d_in[0];
  const float* Wih1 = (const float*)d_in[1];
  const float* Whh1 = (const float*)d_in[2];
  const float* bih1 = (const float*)d_in[3];
  const float* bhh1 = (const float*)d_in[4];
  const float* Wih2 = (const float*)d_in[5];
  const float* Whh2 = (const float*)d_in[6];
  const float* bih2 = (const float*)d_in[7];
  const float* bhh2 = (const float*)d_in[8];
  const float* Wl   = (const float*)d_in[9];
  const float* bl   = (const float*)d_in[10];

  const int Btot = in_sizes[0] / Tt;   // 32768
  dim3 grid(Btot / 16), block(64);
  hipLaunchKernelGGL(lstm_fused, grid, block, 0, stream,
                     inp, Wih1, Whh1, bih1, bhh1, Wih2, Whh2, bih2, bhh2, Wl, bl,
                     (float*)d_out, Btot);
}

// Round 7
// 330.996 us; speedup vs baseline: 1.1962x; 1.1962x over previous
//
#include <hip/hip_runtime.h>

typedef __fp16 mf16x8 __attribute__((ext_vector_type(8)));
typedef float f32x4 __attribute__((ext_vector_type(4)));

#define Tt 187
#define IST 189   // ibuf row stride (f32)
#define L2E 1.44269504088896340736f

// ---- paired activations: two independent inputs share one v_rcp ----
__device__ __forceinline__ void sigm2(float xA, float xB, float& sA, float& sB) {
  float eA = __builtin_amdgcn_exp2f(xA * -L2E);
  float eB = __builtin_amdgcn_exp2f(xB * -L2E);
  float dA = 1.f + eA, dB = 1.f + eB;
  float rp = __builtin_amdgcn_rcpf(dA * dB);
  sA = dB * rp;
  sB = dA * rp;
}
__device__ __forceinline__ void tanh2(float xA, float xB, float& tA, float& tB) {
  float cA = fminf(fmaxf(xA, -20.f), 20.f);   // keep dA*dB < f32 max
  float cB = fminf(fmaxf(xB, -20.f), 20.f);
  float eA = __builtin_amdgcn_exp2f(cA * (2.f * L2E));
  float eB = __builtin_amdgcn_exp2f(cB * (2.f * L2E));
  float dA = 1.f + eA, dB = 1.f + eB;
  float rp = __builtin_amdgcn_rcpf(dA * dB);
  tA = fmaf(-2.f * dB, rp, 1.f);
  tB = fmaf(-2.f * dA, rp, 1.f);
}
// single versions (epilogue only, off the hot loop)
__device__ __forceinline__ float sigm(float x) {
  return __builtin_amdgcn_rcpf(1.0f + __builtin_amdgcn_exp2f(x * -L2E));
}

__device__ __forceinline__ unsigned int pkbits(float lo, float hi) {
  return __builtin_bit_cast(unsigned int, __builtin_amdgcn_cvt_pkrtz(lo, hi));
}
// B fragment from this lane's own hn[5] (+ x in slot element 5): k-slot 8g+jt <-> unit 4jt+g
__device__ __forceinline__ mf16x8 mkbf(const float* hn, float xsel) {
  union { unsigned int u[4]; mf16x8 v; } cv;
  cv.u[0] = pkbits(hn[0], hn[1]);
  cv.u[1] = pkbits(hn[2], hn[3]);
  cv.u[2] = pkbits(hn[4], xsel);
  cv.u[3] = 0u;
  return cv.v;
}

// Stage one layer's weights into per-lane MFMA fragments.
// A lane (m = lane&15, ka = lane>>4): j = 16*jt + m -> unit 4*jt+(m>>2), gate m&3.
// k-slot 8*ka+kk: kk<5 -> input unit 4*kk+ka ; slot 21 -> x (Wih) ; else zero pad.
// Bias in D-layout: lane (r, g) reg i -> gate i of unit 4*jt+g.
__device__ __forceinline__ void stage_layer(
    const float* __restrict__ Wih, const float* __restrict__ Whh,
    const float* __restrict__ bih, const float* __restrict__ bhh,
    int m, int g, mf16x8* A, f32x4* Bias)
{
#pragma unroll
  for (int jt = 0; jt < 5; ++jt) {
    const int unitA = 4 * jt + (m >> 2), gateA = m & 3;
    const int trow = gateA * 20 + unitA;          // torch row in [4H]
    union { __fp16 h[8]; mf16x8 v; } av;
#pragma unroll
    for (int kk = 0; kk < 8; ++kk) {
      const int s = 8 * g + kk;
      float w = 0.f;
      if (kk < 5)       w = Whh[trow * 20 + 4 * kk + g];
      else if (s == 21) w = Wih[trow];
      av.h[kk] = (__fp16)w;
    }
    A[jt] = av.v;
    const int u = 4 * jt + g;
    f32x4 bv;
#pragma unroll
    for (int i = 0; i < 4; ++i) bv[i] = bih[i * 20 + u] + bhh[i * 20 + u];
    Bias[jt] = bv;
  }
}

// One LSTM step for TWO independent chains (A/B row-tiles), rcp-paired gates.
__device__ __forceinline__ void cell2(
    const mf16x8* A, const f32x4* Bias, mf16x8 bfA, mf16x8 bfB,
    float* cA_, float* cB_, float* hnA, float* hnB)
{
#pragma unroll
  for (int jt = 0; jt < 5; ++jt) {
    f32x4 aA = __builtin_amdgcn_mfma_f32_16x16x32_f16(A[jt], bfA, Bias[jt], 0, 0, 0);
    f32x4 aB = __builtin_amdgcn_mfma_f32_16x16x32_f16(A[jt], bfB, Bias[jt], 0, 0, 0);
    float iiA, iiB, ffA, ffB, ggA, ggB, ooA, ooB, tcA, tcB;
    sigm2(aA[0], aB[0], iiA, iiB);
    sigm2(aA[1], aB[1], ffA, ffB);
    tanh2(aA[2], aB[2], ggA, ggB);
    sigm2(aA[3], aB[3], ooA, ooB);
    float ccA = fmaf(ffA, cA_[jt], iiA * ggA);
    float ccB = fmaf(ffB, cB_[jt], iiB * ggB);
    cA_[jt] = ccA;
    cB_[jt] = ccB;
    tanh2(ccA, ccB, tcA, tcB);
    hnA[jt] = ooA * tcA;
    hnB[jt] = ooB * tcB;
  }
}

extern "C" __global__ __launch_bounds__(64) void lstm_fused(
    const float* __restrict__ inp,  const float* __restrict__ Wih1,
    const float* __restrict__ Whh1, const float* __restrict__ bih1,
    const float* __restrict__ bhh1, const float* __restrict__ Wih2,
    const float* __restrict__ Whh2, const float* __restrict__ bih2,
    const float* __restrict__ bhh2, const float* __restrict__ Wl,
    const float* __restrict__ bl,   float* __restrict__ out, int Btot)
{
  __shared__ __align__(16) float ibuf[32 * IST];   // read-only input tile (2 chains)

  const int lane = threadIdx.x;
  const int r = lane & 15;      // batch row within each 16-row tile
  const int g = lane >> 4;      // k-chunk / unit-group id
  const int row0 = blockIdx.x * 32;

  // stage input tile (32 rows), coalesced
  {
    const float* src = inp + (size_t)row0 * Tt;
    for (int i = lane; i < 32 * Tt; i += 64) {
      int rr = i / Tt, t = i - rr * Tt;
      ibuf[rr * IST + t] = src[i];
    }
  }

  mf16x8 A1[5]; f32x4 B1[5];
  stage_layer(Wih1, Whh1, bih1, bhh1, r, g, A1, B1);

  float cA_[5], cB_[5], hnA[5], hnB[5];
#pragma unroll
  for (int jt = 0; jt < 5; ++jt) { cA_[jt] = cB_[jt] = 0.f; hnA[jt] = hnB[jt] = 0.f; }

  __syncthreads();

  // ================= encoder: two independent chains, no LDS writes =================
  float xtA = ibuf[r * IST];
  float xtB = ibuf[(16 + r) * IST];
  for (int t = 0; t < Tt; ++t) {
    mf16x8 bfA = mkbf(hnA, (g == 2) ? xtA : 0.f);
    mf16x8 bfB = mkbf(hnB, (g == 2) ? xtB : 0.f);
    cell2(A1, B1, bfA, bfB, cA_, cB_, hnA, hnB);
    if (t + 1 < Tt) {
      xtA = ibuf[r * IST + t + 1];
      xtB = ibuf[(16 + r) * IST + t + 1];
    }
  }

  // ================= log_softmax(h_e), both chains =================
  {
    float mA = hnA[0], mB = hnB[0];
#pragma unroll
    for (int jt = 1; jt < 5; ++jt) { mA = fmaxf(mA, hnA[jt]); mB = fmaxf(mB, hnB[jt]); }
    mA = fmaxf(mA, __shfl_xor(mA, 16, 64)); mB = fmaxf(mB, __shfl_xor(mB, 16, 64));
    mA = fmaxf(mA, __shfl_xor(mA, 32, 64)); mB = fmaxf(mB, __shfl_xor(mB, 32, 64));
    float sA = 0.f, sB = 0.f;
#pragma unroll
    for (int jt = 0; jt < 5; ++jt) {
      sA += __builtin_amdgcn_exp2f((hnA[jt] - mA) * L2E);
      sB += __builtin_amdgcn_exp2f((hnB[jt] - mB) * L2E);
    }
    sA += __shfl_xor(sA, 16, 64); sB += __shfl_xor(sB, 16, 64);
    sA += __shfl_xor(sA, 32, 64); sB += __shfl_xor(sB, 32, 64);
    const float lseA = mA + 0.69314718055994530942f * __builtin_amdgcn_logf(sA);
    const float lseB = mB + 0.69314718055994530942f * __builtin_amdgcn_logf(sB);
    float* out2 = out + (size_t)Btot * Tt;
#pragma unroll
    for (int jt = 0; jt < 5; ++jt) {
      out2[(size_t)(row0 + r) * 20 + 4 * jt + g]      = hnA[jt] - lseA;
      out2[(size_t)(row0 + 16 + r) * 20 + 4 * jt + g] = hnB[jt] - lseB;
    }
  }

  // ================= decoder =================
  mf16x8 A2[5]; f32x4 B2[5];
  stage_layer(Wih2, Whh2, bih2, bhh2, r, g, A2, B2);
  float wl[5];
#pragma unroll
  for (int jt = 0; jt < 5; ++jt) wl[jt] = Wl[4 * jt + g];
  const float blv = bl[0];

  float otA = 0.f, otB = 0.f;
  for (int s = 0; s < Tt; ++s) {
    mf16x8 bfA = mkbf(hnA, (g == 2) ? otA : 0.f);
    mf16x8 bfB = mkbf(hnB, (g == 2) ? otB : 0.f);
    cell2(A2, B2, bfA, bfB, cA_, cB_, hnA, hnB);
    float pA = hnA[0] * wl[0], pB = hnB[0] * wl[0];
#pragma unroll
    for (int jt = 1; jt < 5; ++jt) {
      pA = fmaf(hnA[jt], wl[jt], pA);
      pB = fmaf(hnB[jt], wl[jt], pB);
    }
    pA += __shfl_xor(pA, 16, 64); pB += __shfl_xor(pB, 16, 64);
    pA += __shfl_xor(pA, 32, 64); pB += __shfl_xor(pB, 32, 64);
    sigm2(pA + blv, pB + blv, otA, otB);
    if (g == 0) {
      out[(size_t)(row0 + r) * Tt + (186 - s)]      = otA;   // pre-flipped
      out[(size_t)(row0 + 16 + r) * Tt + (186 - s)] = otB;
    }
  }
}

extern "C" void kernel_launch(void* const* d_in, const int* in_sizes, int n_in,
                              void* d_out, int out_size, void* d_ws, size_t ws_size,
                              hipStream_t stream) {
  const float* inp  = (const float*)d_in[0];
  const float* Wih1 = (const float*)d_in[1];
  const float* Whh1 = (const float*)d_in[2];
  const float* bih1 = (const float*)d_in[3];
  const float* bhh1 = (const float*)d_in[4];
  const float* Wih2 = (const float*)d_in[5];
  const float* Whh2 = (const float*)d_in[6];
  const float* bih2 = (const float*)d_in[7];
  const float* bhh2 = (const float*)d_in[8];
  const float* Wl   = (const float*)d_in[9];
  const float* bl   = (const float*)d_in[10];

  const int Btot = in_sizes[0] / Tt;   // 32768
  dim3 grid(Btot / 32), block(64);
  hipLaunchKernelGGL(lstm_fused, grid, block, 0, stream,
                     inp, Wih1, Whh1, bih1, bhh1, Wih2, Whh2, bih2, bhh2, Wl, bl,
                     (float*)d_out, Btot);
}

// Round 8
// 283.613 us; speedup vs baseline: 1.3960x; 1.1671x over previous
//
#include <hip/hip_runtime.h>

typedef __fp16 mf16x8 __attribute__((ext_vector_type(8)));
typedef float f32x4 __attribute__((ext_vector_type(4)));

#define Tt 187
#define IST 189   // ibuf row stride (f32)
#define L2E 1.44269504088896340736f

// ---- paired activations on PRE-SCALED pre-activations ----
// weights/bias rows are pre-multiplied: i,f,o by -L2E ; g by +2*L2E.
// sigm(x) = rcp(1 + exp2(x'))        with x' = -L2E*x
// tanh(x) = 1 - 2*rcp(1 + exp2(x'')) with x'' = 2*L2E*x
__device__ __forceinline__ void psigm2(float xa, float xb, float& sa, float& sb) {
  float da = 1.f + __builtin_amdgcn_exp2f(xa);
  float db = 1.f + __builtin_amdgcn_exp2f(xb);
  float rp = __builtin_amdgcn_rcpf(da * db);
  sa = db * rp;
  sb = da * rp;
}
__device__ __forceinline__ void ptanh2(float xa, float xb, float& ta, float& tb) {
  float da = 1.f + __builtin_amdgcn_exp2f(xa);
  float db = 1.f + __builtin_amdgcn_exp2f(xb);
  float rp = __builtin_amdgcn_rcpf(da * db);
  float m2 = -2.f * rp;
  ta = fmaf(db, m2, 1.f);
  tb = fmaf(da, m2, 1.f);
}
// mixed pair: tanh(g') and sigm(o') share one rcp
__device__ __forceinline__ void ptanh_sigm(float xg, float xo, float& tg, float& so) {
  float dg = 1.f + __builtin_amdgcn_exp2f(xg);
  float dn = 1.f + __builtin_amdgcn_exp2f(xo);
  float rp = __builtin_amdgcn_rcpf(dg * dn);
  tg = fmaf(dn, -2.f * rp, 1.f);
  so = dg * rp;
}
// paired tanh on RAW cell values (clamp +-16, scale 2*L2E)
__device__ __forceinline__ void ctanh2(float ca, float cb, float& ta, float& tb) {
  float xa = __builtin_amdgcn_fmed3f(ca, -16.f, 16.f) * (2.f * L2E);
  float xb = __builtin_amdgcn_fmed3f(cb, -16.f, 16.f) * (2.f * L2E);
  ptanh2(xa, xb, ta, tb);
}

__device__ __forceinline__ unsigned int pkbits(float lo, float hi) {
  return __builtin_bit_cast(unsigned int, __builtin_amdgcn_cvt_pkrtz(lo, hi));
}
// B fragment from this lane's own hn[5] (+ x in slot element 5): k-slot 8g+jt <-> unit 4jt+g
__device__ __forceinline__ mf16x8 mkbf(const float* hn, float xsel) {
  union { unsigned int u[4]; mf16x8 v; } cv;
  cv.u[0] = pkbits(hn[0], hn[1]);
  cv.u[1] = pkbits(hn[2], hn[3]);
  cv.u[2] = pkbits(hn[4], xsel);
  cv.u[3] = 0u;
  return cv.v;
}

// Stage one layer's weights into per-lane MFMA fragments, PRE-SCALED per gate.
// A lane (m = lane&15, ka = lane>>4): j = 16*jt + m -> unit 4*jt+(m>>2), gate m&3.
// k-slot 8*ka+kk: kk<5 -> input unit 4*kk+ka ; slot 21 -> x (Wih) ; else zero pad.
// Bias in D-layout: lane (r, g) reg i -> gate i of unit 4*jt+g.
__device__ __forceinline__ void stage_layer(
    const float* __restrict__ Wih, const float* __restrict__ Whh,
    const float* __restrict__ bih, const float* __restrict__ bhh,
    int m, int g, mf16x8* A, f32x4* Bias)
{
  const int gateA = m & 3;
  const float scA = (gateA == 2) ? (2.f * L2E) : -L2E;   // gate g vs i/f/o
#pragma unroll
  for (int jt = 0; jt < 5; ++jt) {
    const int unitA = 4 * jt + (m >> 2);
    const int trow = gateA * 20 + unitA;          // torch row in [4H]
    union { __fp16 h[8]; mf16x8 v; } av;
#pragma unroll
    for (int kk = 0; kk < 8; ++kk) {
      const int s = 8 * g + kk;
      float w = 0.f;
      if (kk < 5)       w = Whh[trow * 20 + 4 * kk + g];
      else if (s == 21) w = Wih[trow];
      av.h[kk] = (__fp16)(w * scA);
    }
    A[jt] = av.v;
    const int u = 4 * jt + g;
    f32x4 bv;
#pragma unroll
    for (int i = 0; i < 4; ++i) {
      const float sc = (i == 2) ? (2.f * L2E) : -L2E;
      bv[i] = (bih[i * 20 + u] + bhh[i * 20 + u]) * sc;
    }
    Bias[jt] = bv;
  }
}

// Gates for a PAIR of units (JA, JB) with pre-scaled accs; 15 trans / pair.
#define GPAIR(accA, accB, JA, JB) do {                     \
    float iA, fA, iB, fB, gA, gB, oA, oB, tA, tB;          \
    psigm2((accA)[0], (accA)[1], iA, fA);                  \
    psigm2((accB)[0], (accB)[1], iB, fB);                  \
    ptanh2((accA)[2], (accB)[2], gA, gB);                  \
    psigm2((accA)[3], (accB)[3], oA, oB);                  \
    float cA = fmaf(fA, c_[JA], iA * gA);                  \
    float cB = fmaf(fB, c_[JB], iB * gB);                  \
    c_[JA] = cA; c_[JB] = cB;                              \
    ctanh2(cA, cB, tA, tB);                                \
    hn[JA] = oA * tA; hn[JB] = oB * tB;                    \
  } while (0)

// Last unit (jt=4): i/f pair, g/o mixed pair, single c-tanh; 8 trans.
#define GLAST(acc4) do {                                               \
    float i4, f4, g4, o4;                                              \
    psigm2((acc4)[0], (acc4)[1], i4, f4);                              \
    ptanh_sigm((acc4)[2], (acc4)[3], g4, o4);                          \
    float c4 = fmaf(f4, c_[4], i4 * g4);                               \
    c_[4] = c4;                                                        \
    float s4 = __builtin_amdgcn_fmed3f(c4, -16.f, 16.f) * (2.f * L2E); \
    float d4 = 1.f + __builtin_amdgcn_exp2f(s4);                       \
    float t4 = fmaf(__builtin_amdgcn_rcpf(d4), -2.f, 1.f);             \
    hn[4] = o4 * t4;                                                   \
  } while (0)

// One full LSTM step: 5 MFMAs first (max trans ILP), then paired gates.
#define STEP(A, B, bf) do {                                                     \
    f32x4 a0 = __builtin_amdgcn_mfma_f32_16x16x32_f16((A)[0], bf, (B)[0], 0, 0, 0); \
    f32x4 a1 = __builtin_amdgcn_mfma_f32_16x16x32_f16((A)[1], bf, (B)[1], 0, 0, 0); \
    f32x4 a2 = __builtin_amdgcn_mfma_f32_16x16x32_f16((A)[2], bf, (B)[2], 0, 0, 0); \
    f32x4 a3 = __builtin_amdgcn_mfma_f32_16x16x32_f16((A)[3], bf, (B)[3], 0, 0, 0); \
    f32x4 a4 = __builtin_amdgcn_mfma_f32_16x16x32_f16((A)[4], bf, (B)[4], 0, 0, 0); \
    GPAIR(a0, a1, 0, 1);                                                        \
    GPAIR(a2, a3, 2, 3);                                                        \
    GLAST(a4);                                                                  \
  } while (0)

extern "C" __global__ __launch_bounds__(64) void lstm_fused(
    const float* __restrict__ inp,  const float* __restrict__ Wih1,
    const float* __restrict__ Whh1, const float* __restrict__ bih1,
    const float* __restrict__ bhh1, const float* __restrict__ Wih2,
    const float* __restrict__ Whh2, const float* __restrict__ bih2,
    const float* __restrict__ bhh2, const float* __restrict__ Wl,
    const float* __restrict__ bl,   float* __restrict__ out, int Btot)
{
  __shared__ __align__(16) float ibuf[16 * IST];   // read-only input tile

  const int lane = threadIdx.x;
  const int r = lane & 15;      // batch row within the wave's 16-row tile
  const int g = lane >> 4;      // k-chunk / unit-group id
  const int row0 = blockIdx.x * 16;

  // stage input tile, coalesced
  {
    const float* src = inp + (size_t)row0 * Tt;
    for (int i = lane; i < 16 * Tt; i += 64) {
      int rr = i / Tt, t = i - rr * Tt;
      ibuf[rr * IST + t] = src[i];
    }
  }

  mf16x8 A1[5]; f32x4 B1[5];
  stage_layer(Wih1, Whh1, bih1, bhh1, r, g, A1, B1);

  float c_[5], hn[5];
#pragma unroll
  for (int jt = 0; jt < 5; ++jt) { c_[jt] = 0.f; hn[jt] = 0.f; }

  __syncthreads();

  // ================= encoder (no LDS writes, no barriers) =================
  float xt = ibuf[r * IST];
  for (int t = 0; t < Tt; ++t) {
    float xnext = (t + 1 < Tt) ? ibuf[r * IST + t + 1] : 0.f;  // prefetch
    mf16x8 bf = mkbf(hn, (g == 2) ? xt : 0.f);
    STEP(A1, B1, bf);
    xt = xnext;
  }

  // ================= log_softmax(h_e) =================
  {
    float m = hn[0];
#pragma unroll
    for (int jt = 1; jt < 5; ++jt) m = fmaxf(m, hn[jt]);
    m = fmaxf(m, __shfl_xor(m, 16, 64));
    m = fmaxf(m, __shfl_xor(m, 32, 64));
    float s = 0.f;
#pragma unroll
    for (int jt = 0; jt < 5; ++jt) s += __builtin_amdgcn_exp2f((hn[jt] - m) * L2E);
    s += __shfl_xor(s, 16, 64);
    s += __shfl_xor(s, 32, 64);
    const float lse = m + 0.69314718055994530942f * __builtin_amdgcn_logf(s);
    float* out2 = out + (size_t)Btot * Tt;
#pragma unroll
    for (int jt = 0; jt < 5; ++jt)
      out2[(size_t)(row0 + r) * 20 + 4 * jt + g] = hn[jt] - lse;
  }

  // ================= decoder =================
  mf16x8 A2[5]; f32x4 B2[5];
  stage_layer(Wih2, Whh2, bih2, bhh2, r, g, A2, B2);
  float wl[5];
#pragma unroll
  for (int jt = 0; jt < 5; ++jt) wl[jt] = Wl[4 * jt + g] * -L2E;  // pre-scaled
  const float blv = bl[0] * -L2E;

  float ot = 0.f;
  for (int s = 0; s < Tt; ++s) {
    mf16x8 bf = mkbf(hn, (g == 2) ? ot : 0.f);
    STEP(A2, B2, bf);
    float p = fmaf(hn[0], wl[0], blv);
#pragma unroll
    for (int jt = 1; jt < 5; ++jt) p = fmaf(hn[jt], wl[jt], p);
    p += __shfl_xor(p, 16, 64);
    p += __shfl_xor(p, 32, 64);
    ot = __builtin_amdgcn_rcpf(1.f + __builtin_amdgcn_exp2f(p));  // p pre-scaled
    if (g == 0) out[(size_t)(row0 + r) * Tt + (186 - s)] = ot;    // pre-flipped store
  }
}

extern "C" void kernel_launch(void* const* d_in, const int* in_sizes, int n_in,
                              void* d_out, int out_size, void* d_ws, size_t ws_size,
                              hipStream_t stream) {
  const float* inp  = (const float*)d_in[0];
  const float* Wih1 = (const float*)d_in[1];
  const float* Whh1 = (const float*)d_in[2];
  const float* bih1 = (const float*)d_in[3];
  const float* bhh1 = (const float*)d_in[4];
  const float* Wih2 = (const float*)d_in[5];
  const float* Whh2 = (const float*)d_in[6];
  const float* bih2 = (const float*)d_in[7];
  const float* bhh2 = (const float*)d_in[8];
  const float* Wl   = (const float*)d_in[9];
  const float* bl   = (const float*)d_in[10];

  const int Btot = in_sizes[0] / Tt;   // 32768
  dim3 grid(Btot / 16), block(64);
  hipLaunchKernelGGL(lstm_fused, grid, block, 0, stream,
                     inp, Wih1, Whh1, bih1, bhh1, Wih2, Whh2, bih2, bhh2, Wl, bl,
                     (float*)d_out, Btot);
}